// Round 2
// baseline (1182.654 us; speedup 1.0000x reference)
//
#include <hip/hip_runtime.h>
#include <hip/hip_fp16.h>

#define NNODES 100000
#define NEG_SLOPE 0.2f

// ---------------- CSR build ----------------

__global__ void k_hist(const int* __restrict__ dst, int* __restrict__ counts, int E) {
    int i = blockIdx.x * blockDim.x + threadIdx.x;
    if (i < E) atomicAdd(&counts[dst[i]], 1);
}

__global__ void k_scanA(const int* __restrict__ counts, int* __restrict__ offs,
                        int* __restrict__ bsums, int N) {
    __shared__ int buf[2][256];
    int t = threadIdx.x;
    int idx = blockIdx.x * 256 + t;
    int v = (idx < N) ? counts[idx] : 0;
    buf[0][t] = v;
    __syncthreads();
    int pi = 0;
    for (int d = 1; d < 256; d <<= 1) {
        int po = pi ^ 1;
        buf[po][t] = buf[pi][t] + (t >= d ? buf[pi][t - d] : 0);
        pi = po;
        __syncthreads();
    }
    if (idx < N) offs[idx] = buf[pi][t] - v;
    if (t == 255) bsums[blockIdx.x] = buf[pi][255];
}

__global__ void k_scanB(int* __restrict__ bsums, int nb) {
    __shared__ int buf[2][512];
    int t = threadIdx.x;
    int v = (t < nb) ? bsums[t] : 0;
    buf[0][t] = v;
    __syncthreads();
    int pi = 0;
    for (int d = 1; d < 512; d <<= 1) {
        int po = pi ^ 1;
        buf[po][t] = buf[pi][t] + (t >= d ? buf[pi][t - d] : 0);
        pi = po;
        __syncthreads();
    }
    if (t < nb) bsums[t] = buf[pi][t] - v;
}

__global__ void k_scanC(int* __restrict__ offs, const int* __restrict__ bsums, int N, int E) {
    int idx = blockIdx.x * 256 + threadIdx.x;
    if (idx < N) offs[idx] += bsums[blockIdx.x];
    if (idx == 0) offs[N] = E;
}

__global__ void k_scatter(const int* __restrict__ src, const int* __restrict__ dst,
                          const int* __restrict__ offs, int* __restrict__ cursor,
                          int* __restrict__ csr_src, int E) {
    int i = blockIdx.x * blockDim.x + threadIdx.x;
    if (i < E) {
        int d = dst[i];
        int pos = offs[d] + atomicAdd(&cursor[d], 1);
        csr_src[pos] = src[i];
    }
}

// ---------------- fused GEMM + attention projections ----------------
// 4 rows per wave: each LDS W-read feeds 4 FMAs. lane = output feature.

template <int FIN>
__global__ __launch_bounds__(256) void k_gemm(const float* __restrict__ x,
                                              const float* __restrict__ W,
                                              const float* __restrict__ al,
                                              const float* __restrict__ ar,
                                              __half* __restrict__ h,
                                              float* __restrict__ el,
                                              float* __restrict__ er, int N) {
    __shared__ float Wl[FIN * 64];
    for (int i = threadIdx.x; i < FIN * 16; i += 256)
        ((float4*)Wl)[i] = ((const float4*)W)[i];
    __syncthreads();

    int wave = threadIdx.x >> 6, lane = threadIdx.x & 63;
    int row0 = (blockIdx.x * 4 + wave) * 4;
    if (row0 >= N) return;

    int nrow = N - row0;
    if (nrow > 4) nrow = 4;

    const float4* xr = (const float4*)(x + (size_t)row0 * FIN);
    float acc[4] = {0.f, 0.f, 0.f, 0.f};

#pragma unroll
    for (int k4 = 0; k4 < FIN / 4; ++k4) {
        float4 xv[4];
#pragma unroll
        for (int r = 0; r < 4; ++r)
            xv[r] = (r < nrow) ? xr[r * (FIN / 4) + k4] : make_float4(0.f, 0.f, 0.f, 0.f);
        const float* wp = Wl + (4 * k4) * 64 + lane;
        float w0 = wp[0], w1 = wp[64], w2 = wp[128], w3 = wp[192];
#pragma unroll
        for (int r = 0; r < 4; ++r) {
            acc[r] = fmaf(xv[r].x, w0, acc[r]);
            acc[r] = fmaf(xv[r].y, w1, acc[r]);
            acc[r] = fmaf(xv[r].z, w2, acc[r]);
            acc[r] = fmaf(xv[r].w, w3, acc[r]);
        }
    }

    float all = al[lane], arl = ar[lane];
#pragma unroll
    for (int r = 0; r < 4; ++r) {
        if (r >= nrow) break;
        h[(size_t)(row0 + r) * 64 + lane] = __float2half(acc[r]);
        float e1 = acc[r] * all;
        float e2 = acc[r] * arl;
#pragma unroll
        for (int o = 32; o; o >>= 1) {
            e1 += __shfl_xor(e1, o);
            e2 += __shfl_xor(e2, o);
        }
        if (lane == 0) {
            el[row0 + r] = e1;
            er[row0 + r] = e2;
        }
    }
}

// ---------------- edge softmax + aggregation ----------------
// One wave per dst node. deg<=64 fast path: lane-owned edge, single pass,
// shuffle-broadcast alpha/src, 4-deep batched h-gather.

__global__ __launch_bounds__(256) void k_agg(const __half* __restrict__ h,
                                             const float* __restrict__ el,
                                             const float* __restrict__ er,
                                             const float* __restrict__ b,
                                             const int* __restrict__ offs,
                                             const int* __restrict__ csr_src,
                                             float* __restrict__ out, int N, int relu) {
    int wave = threadIdx.x >> 6, lane = threadIdx.x & 63;
    int n = blockIdx.x * 4 + wave;
    if (n >= N) return;

    int beg = offs[n], end = offs[n + 1];
    int deg = end - beg;
    float ern = er[n];
    float acc;

    if (deg <= 64) {
        int sidx = 0;
        float e = -1e30f;
        if (lane < deg) {
            sidx = csr_src[beg + lane];
            e = el[sidx] + ern;
            e = e > 0.f ? e : NEG_SLOPE * e;
        }
        float m = e;
#pragma unroll
        for (int o = 32; o; o >>= 1) m = fmaxf(m, __shfl_xor(m, o));
        float p = (lane < deg) ? __expf(e - m) : 0.f;
        float s = p;
#pragma unroll
        for (int o = 32; o; o >>= 1) s += __shfl_xor(s, o);
        float a = p * (1.f / fmaxf(s, 1e-9f));

        const __half* hb = h + lane;
        float a0 = 0.f, a1 = 0.f, a2 = 0.f, a3 = 0.f;
        int i = 0;
        for (; i + 4 <= deg; i += 4) {
            int s0 = __shfl(sidx, i), s1 = __shfl(sidx, i + 1);
            int s2 = __shfl(sidx, i + 2), s3 = __shfl(sidx, i + 3);
            float w0 = __shfl(a, i), w1 = __shfl(a, i + 1);
            float w2 = __shfl(a, i + 2), w3 = __shfl(a, i + 3);
            float h0 = __half2float(hb[(size_t)s0 * 64]);
            float h1 = __half2float(hb[(size_t)s1 * 64]);
            float h2 = __half2float(hb[(size_t)s2 * 64]);
            float h3 = __half2float(hb[(size_t)s3 * 64]);
            a0 = fmaf(w0, h0, a0);
            a1 = fmaf(w1, h1, a1);
            a2 = fmaf(w2, h2, a2);
            a3 = fmaf(w3, h3, a3);
        }
        for (; i < deg; ++i) {
            int s0 = __shfl(sidx, i);
            float w0 = __shfl(a, i);
            a0 = fmaf(w0, __half2float(hb[(size_t)s0 * 64]), a0);
        }
        acc = (a0 + a1) + (a2 + a3);
    } else {
        float m = -1e30f;
        for (int i = beg + lane; i < end; i += 64) {
            float e = el[csr_src[i]] + ern;
            e = e > 0.f ? e : NEG_SLOPE * e;
            m = fmaxf(m, e);
        }
#pragma unroll
        for (int o = 32; o; o >>= 1) m = fmaxf(m, __shfl_xor(m, o));
        float s = 0.f;
        for (int i = beg + lane; i < end; i += 64) {
            float e = el[csr_src[i]] + ern;
            e = e > 0.f ? e : NEG_SLOPE * e;
            s += __expf(e - m);
        }
#pragma unroll
        for (int o = 32; o; o >>= 1) s += __shfl_xor(s, o);
        float inv = 1.f / fmaxf(s, 1e-9f);
        acc = 0.f;
        for (int i = beg; i < end; ++i) {
            int sidx = csr_src[i];
            float e = el[sidx] + ern;
            e = e > 0.f ? e : NEG_SLOPE * e;
            float a = __expf(e - m) * inv;
            acc = fmaf(a, __half2float(h[(size_t)sidx * 64 + lane]), acc);
        }
    }

    float o = acc + b[lane];
    if (relu) o = fmaxf(o, 0.f);
    out[(size_t)n * 64 + lane] = o;
}

// ---------------- launch ----------------

extern "C" void kernel_launch(void* const* d_in, const int* in_sizes, int n_in,
                              void* d_out, int out_size, void* d_ws, size_t ws_size,
                              hipStream_t stream) {
    const float* x   = (const float*)d_in[0];
    const int*   src = (const int*)d_in[1];
    const int*   dst = (const int*)d_in[2];
    const float* W1  = (const float*)d_in[3];
    const float* al1 = (const float*)d_in[4];
    const float* ar1 = (const float*)d_in[5];
    const float* b1  = (const float*)d_in[6];
    const float* W2  = (const float*)d_in[7];
    const float* al2 = (const float*)d_in[8];
    const float* ar2 = (const float*)d_in[9];
    const float* b2  = (const float*)d_in[10];
    float* out = (float*)d_out;

    const int N = NNODES;
    const int E = in_sizes[1];

    // workspace layout
    __half* h   = (__half*)d_ws;                       // N*64 halfs (12.8MB)
    float* hmid = (float*)(h + (size_t)N * 64);        // N*64 floats
    float* el   = hmid + (size_t)N * 64;               // N
    float* er   = el + N;                              // N
    int* counts = (int*)(er + N);                      // N
    int* cursor = counts + N;                          // N
    int* offs   = cursor + N;                          // N+1
    int* csrs   = offs + N + 1;                        // E
    int* bsums  = csrs + E;                            // <=512

    int nbN = (N + 255) / 256;   // 391 (<=512 for scanB)
    int nbE = (E + 255) / 256;

    hipMemsetAsync(counts, 0, (size_t)N * sizeof(int), stream);
    hipMemsetAsync(cursor, 0, (size_t)N * sizeof(int), stream);

    k_hist<<<nbE, 256, 0, stream>>>(dst, counts, E);
    k_scanA<<<nbN, 256, 0, stream>>>(counts, offs, bsums, N);
    k_scanB<<<1, 512, 0, stream>>>(bsums, nbN);
    k_scanC<<<nbN, 256, 0, stream>>>(offs, bsums, N, E);
    k_scatter<<<nbE, 256, 0, stream>>>(src, dst, offs, cursor, csrs, E);

    int nbR = (N + 3) / 4;       // k_agg: wave per node
    int nbG = (N + 15) / 16;     // k_gemm: 16 rows per block
    // layer 1
    k_gemm<128><<<nbG, 256, 0, stream>>>(x, W1, al1, ar1, h, el, er, N);
    k_agg<<<nbR, 256, 0, stream>>>(h, el, er, b1, offs, csrs, hmid, N, 1);
    // layer 2
    k_gemm<64><<<nbG, 256, 0, stream>>>(hmid, W2, al2, ar2, h, el, er, N);
    k_agg<<<nbR, 256, 0, stream>>>(h, el, er, b2, offs, csrs, out, N, 0);
}

// Round 4
// 447.092 us; speedup vs baseline: 2.6452x; 2.6452x over previous
//
#include <hip/hip_runtime.h>
#include <hip/hip_fp16.h>

#define NNODES 100000
#define NEG_SLOPE 0.2f

// ---------------- CSR build ----------------

__global__ void k_hist(const int* __restrict__ dst, int* __restrict__ counts, int E) {
    int i = blockIdx.x * blockDim.x + threadIdx.x;
    if (i < E) atomicAdd(&counts[dst[i]], 1);
}

__global__ void k_scanA(const int* __restrict__ counts, int* __restrict__ offs,
                        int* __restrict__ bsums, int N) {
    __shared__ int buf[2][256];
    int t = threadIdx.x;
    int idx = blockIdx.x * 256 + t;
    int v = (idx < N) ? counts[idx] : 0;
    buf[0][t] = v;
    __syncthreads();
    int pi = 0;
    for (int d = 1; d < 256; d <<= 1) {
        int po = pi ^ 1;
        buf[po][t] = buf[pi][t] + (t >= d ? buf[pi][t - d] : 0);
        pi = po;
        __syncthreads();
    }
    if (idx < N) offs[idx] = buf[pi][t] - v;
    if (t == 255) bsums[blockIdx.x] = buf[pi][255];
}

__global__ void k_scanB(int* __restrict__ bsums, int nb) {
    __shared__ int buf[2][512];
    int t = threadIdx.x;
    int v = (t < nb) ? bsums[t] : 0;
    buf[0][t] = v;
    __syncthreads();
    int pi = 0;
    for (int d = 1; d < 512; d <<= 1) {
        int po = pi ^ 1;
        buf[po][t] = buf[pi][t] + (t >= d ? buf[pi][t - d] : 0);
        pi = po;
        __syncthreads();
    }
    if (t < nb) bsums[t] = buf[pi][t] - v;
}

__global__ void k_scanC(int* __restrict__ offs, const int* __restrict__ bsums, int N, int E) {
    int idx = blockIdx.x * 256 + threadIdx.x;
    if (idx < N) offs[idx] += bsums[blockIdx.x];
    if (idx == 0) offs[N] = E;
}

__global__ void k_scatter(const int* __restrict__ src, const int* __restrict__ dst,
                          const int* __restrict__ offs, int* __restrict__ cursor,
                          int* __restrict__ csr_src, int E) {
    int i = blockIdx.x * blockDim.x + threadIdx.x;
    if (i < E) {
        int d = dst[i];
        int pos = offs[d] + atomicAdd(&cursor[d], 1);
        csr_src[pos] = src[i];
    }
}

// ---------------- fused GEMM + attention projections ----------------
// 4 rows per wave, lane = output feature. W in LDS; each W read feeds 4 FMAs.
// N % 16 == 0 -> no tail guards. Bounded unroll + launch_bounds(256,4)
// (VGPR cap 128) to avoid the round-2 spill catastrophe.

template <int FIN>
__global__ __launch_bounds__(256, 4) void k_gemm(const float* __restrict__ x,
                                                 const float* __restrict__ W,
                                                 const float* __restrict__ al,
                                                 const float* __restrict__ ar,
                                                 __half* __restrict__ h,
                                                 float* __restrict__ el,
                                                 float* __restrict__ er, int N) {
    __shared__ float Wl[FIN * 64];
    for (int i = threadIdx.x; i < FIN * 16; i += 256)
        ((float4*)Wl)[i] = ((const float4*)W)[i];
    __syncthreads();

    int wave = threadIdx.x >> 6, lane = threadIdx.x & 63;
    int row0 = (blockIdx.x * 4 + wave) * 4;
    if (row0 >= N) return;

    const float* xp = x + (size_t)row0 * FIN;
    float acc[4] = {0.f, 0.f, 0.f, 0.f};

#pragma unroll 4
    for (int k4 = 0; k4 < FIN / 4; ++k4) {
        const float* wp = Wl + 4 * k4 * 64 + lane;
        float w0 = wp[0], w1 = wp[64], w2 = wp[128], w3 = wp[192];
#pragma unroll
        for (int r = 0; r < 4; ++r) {
            float4 xv = *(const float4*)(xp + (size_t)r * FIN + 4 * k4);
            acc[r] = fmaf(xv.x, w0, acc[r]);
            acc[r] = fmaf(xv.y, w1, acc[r]);
            acc[r] = fmaf(xv.z, w2, acc[r]);
            acc[r] = fmaf(xv.w, w3, acc[r]);
        }
    }

    float all = al[lane], arl = ar[lane];
#pragma unroll
    for (int r = 0; r < 4; ++r) {
        h[(size_t)(row0 + r) * 64 + lane] = __float2half(acc[r]);
        float e1 = acc[r] * all;
        float e2 = acc[r] * arl;
#pragma unroll
        for (int o = 32; o; o >>= 1) {
            e1 += __shfl_xor(e1, o);
            e2 += __shfl_xor(e2, o);
        }
        if (lane == 0) {
            el[row0 + r] = e1;
            er[row0 + r] = e2;
        }
    }
}

// ---------------- edge softmax + aggregation ----------------
// One wave per dst node.
// Softmax (deg<=64): lane-owned edge, single pass, shuffle reduce.
// Gather: 4 groups x 16 lanes; group g handles edges g, g+4, ...
// CRITICAL: the gather loop trip count MUST be wave-uniform. __shfl is
// ds_bpermute, which returns UNDEFINED data when the source lane is
// inactive (round-3 bug: per-group exit conditions made late iterations
// read lanes of already-exited groups). All 64 lanes run iters=ceil(deg/4)
// iterations; lanes i>=deg hold a=0/sidx=0 so extras contribute exactly 0.

__device__ inline float2 h2_to_f2(float bits) {
    return __half22float2(__builtin_bit_cast(__half2, bits));
}

__global__ __launch_bounds__(256) void k_agg(const __half* __restrict__ h,
                                             const float* __restrict__ el,
                                             const float* __restrict__ er,
                                             const float* __restrict__ b,
                                             const int* __restrict__ offs,
                                             const int* __restrict__ csr_src,
                                             float* __restrict__ out, int N, int relu) {
    int wave = threadIdx.x >> 6, lane = threadIdx.x & 63;
    int n = blockIdx.x * 4 + wave;
    if (n >= N) return;

    int beg = offs[n], end = offs[n + 1];
    int deg = end - beg;
    float ern = er[n];

    int g = lane >> 4;    // edge group 0..3
    int fl = lane & 15;   // feature lane: features 4*fl .. 4*fl+3
    float4 accv = make_float4(0.f, 0.f, 0.f, 0.f);
    const size_t foff = 4 * (size_t)fl;

    if (deg <= 64) {
        int sidx = 0;
        float e = -1e30f;
        if (lane < deg) {
            sidx = csr_src[beg + lane];
            e = el[sidx] + ern;
            e = e > 0.f ? e : NEG_SLOPE * e;
        }
        float m = e;
#pragma unroll
        for (int o = 32; o; o >>= 1) m = fmaxf(m, __shfl_xor(m, o));
        float p = (lane < deg) ? __expf(e - m) : 0.f;
        float s = p;
#pragma unroll
        for (int o = 32; o; o >>= 1) s += __shfl_xor(s, o);
        float a = p * (1.f / fmaxf(s, 1e-9f));

        int iters = (deg + 3) >> 2;   // wave-uniform per-group trip count
        int pair = iters >> 1;
        int i = g;
        for (int t2 = 0; t2 < pair; ++t2, i += 8) {
            int s0 = __shfl(sidx, i), s1 = __shfl(sidx, i + 4);
            float w0 = __shfl(a, i), w1 = __shfl(a, i + 4);
            float2 r0 = *(const float2*)(h + (size_t)s0 * 64 + foff);
            float2 r1 = *(const float2*)(h + (size_t)s1 * 64 + foff);
            float2 f00 = h2_to_f2(r0.x), f01 = h2_to_f2(r0.y);
            float2 f10 = h2_to_f2(r1.x), f11 = h2_to_f2(r1.y);
            accv.x = fmaf(w0, f00.x, accv.x); accv.y = fmaf(w0, f00.y, accv.y);
            accv.z = fmaf(w0, f01.x, accv.z); accv.w = fmaf(w0, f01.y, accv.w);
            accv.x = fmaf(w1, f10.x, accv.x); accv.y = fmaf(w1, f10.y, accv.y);
            accv.z = fmaf(w1, f11.x, accv.z); accv.w = fmaf(w1, f11.y, accv.w);
        }
        if (iters & 1) {
            int s0 = __shfl(sidx, i);
            float w0 = __shfl(a, i);
            float2 r0 = *(const float2*)(h + (size_t)s0 * 64 + foff);
            float2 f00 = h2_to_f2(r0.x), f01 = h2_to_f2(r0.y);
            accv.x = fmaf(w0, f00.x, accv.x); accv.y = fmaf(w0, f00.y, accv.y);
            accv.z = fmaf(w0, f01.x, accv.z); accv.w = fmaf(w0, f01.y, accv.w);
        }
    } else {
        float m = -1e30f;
        for (int i = beg + lane; i < end; i += 64) {
            float e = el[csr_src[i]] + ern;
            e = e > 0.f ? e : NEG_SLOPE * e;
            m = fmaxf(m, e);
        }
#pragma unroll
        for (int o = 32; o; o >>= 1) m = fmaxf(m, __shfl_xor(m, o));
        float s = 0.f;
        for (int i = beg + lane; i < end; i += 64) {
            float e = el[csr_src[i]] + ern;
            e = e > 0.f ? e : NEG_SLOPE * e;
            s += __expf(e - m);
        }
#pragma unroll
        for (int o = 32; o; o >>= 1) s += __shfl_xor(s, o);
        float inv = 1.f / fmaxf(s, 1e-9f);

        for (int i = g; i < deg; i += 4) {      // no shuffles inside: safe
            int s0 = csr_src[beg + i];          // 16-lane broadcast load
            float e = el[s0] + ern;
            e = e > 0.f ? e : NEG_SLOPE * e;
            float w0 = __expf(e - m) * inv;
            float2 r0 = *(const float2*)(h + (size_t)s0 * 64 + foff);
            float2 f00 = h2_to_f2(r0.x), f01 = h2_to_f2(r0.y);
            accv.x = fmaf(w0, f00.x, accv.x); accv.y = fmaf(w0, f00.y, accv.y);
            accv.z = fmaf(w0, f01.x, accv.z); accv.w = fmaf(w0, f01.y, accv.w);
        }
    }

    // combine the 4 edge-groups (re-converged; all 64 lanes active)
#pragma unroll
    for (int o = 16; o <= 32; o <<= 1) {
        accv.x += __shfl_xor(accv.x, o);
        accv.y += __shfl_xor(accv.y, o);
        accv.z += __shfl_xor(accv.z, o);
        accv.w += __shfl_xor(accv.w, o);
    }

    if (lane < 16) {
        float4 bv = *(const float4*)(b + foff);
        float4 o4;
        o4.x = accv.x + bv.x;
        o4.y = accv.y + bv.y;
        o4.z = accv.z + bv.z;
        o4.w = accv.w + bv.w;
        if (relu) {
            o4.x = fmaxf(o4.x, 0.f); o4.y = fmaxf(o4.y, 0.f);
            o4.z = fmaxf(o4.z, 0.f); o4.w = fmaxf(o4.w, 0.f);
        }
        *(float4*)(out + (size_t)n * 64 + foff) = o4;
    }
}

// ---------------- launch ----------------

extern "C" void kernel_launch(void* const* d_in, const int* in_sizes, int n_in,
                              void* d_out, int out_size, void* d_ws, size_t ws_size,
                              hipStream_t stream) {
    const float* x   = (const float*)d_in[0];
    const int*   src = (const int*)d_in[1];
    const int*   dst = (const int*)d_in[2];
    const float* W1  = (const float*)d_in[3];
    const float* al1 = (const float*)d_in[4];
    const float* ar1 = (const float*)d_in[5];
    const float* b1  = (const float*)d_in[6];
    const float* W2  = (const float*)d_in[7];
    const float* al2 = (const float*)d_in[8];
    const float* ar2 = (const float*)d_in[9];
    const float* b2  = (const float*)d_in[10];
    float* out = (float*)d_out;

    const int N = NNODES;
    const int E = in_sizes[1];

    // workspace layout
    __half* h   = (__half*)d_ws;                       // N*64 halfs (12.8MB)
    float* hmid = (float*)(h + (size_t)N * 64);        // N*64 floats
    float* el   = hmid + (size_t)N * 64;               // N
    float* er   = el + N;                              // N
    int* counts = (int*)(er + N);                      // N
    int* cursor = counts + N;                          // N
    int* offs   = cursor + N;                          // N+1
    int* csrs   = offs + N + 1;                        // E
    int* bsums  = csrs + E;                            // <=512

    int nbN = (N + 255) / 256;   // 391 (<=512 for scanB)
    int nbE = (E + 255) / 256;

    hipMemsetAsync(counts, 0, (size_t)N * sizeof(int), stream);
    hipMemsetAsync(cursor, 0, (size_t)N * sizeof(int), stream);

    k_hist<<<nbE, 256, 0, stream>>>(dst, counts, E);
    k_scanA<<<nbN, 256, 0, stream>>>(counts, offs, bsums, N);
    k_scanB<<<1, 512, 0, stream>>>(bsums, nbN);
    k_scanC<<<nbN, 256, 0, stream>>>(offs, bsums, N, E);
    k_scatter<<<nbE, 256, 0, stream>>>(src, dst, offs, cursor, csrs, E);

    int nbR = (N + 3) / 4;       // k_agg: wave per node
    int nbG = (N + 15) / 16;     // k_gemm: 16 rows per block
    // layer 1
    k_gemm<128><<<nbG, 256, 0, stream>>>(x, W1, al1, ar1, h, el, er, N);
    k_agg<<<nbR, 256, 0, stream>>>(h, el, er, b1, offs, csrs, hmid, N, 1);
    // layer 2
    k_gemm<64><<<nbG, 256, 0, stream>>>(hmid, W2, al2, ar2, h, el, er, N);
    k_agg<<<nbR, 256, 0, stream>>>(h, el, er, b2, offs, csrs, out, N, 0);
}

// Round 5
// 288.424 us; speedup vs baseline: 4.1004x; 1.5501x over previous
//
#include <hip/hip_runtime.h>
#include <hip/hip_fp16.h>

#define NNODES 100000
#define NEG_SLOPE 0.2f

// ---------------- CSR build ----------------
// k_hist also records each edge's arrival rank within its dst bucket, so the
// later scatter needs NO atomics (round-4: scatter was 128us, half of it
// atomic-return latency; now the atomic rides along with the histogram).

__global__ void k_hist(const int* __restrict__ dst, int* __restrict__ counts,
                       int* __restrict__ rank, int E) {
    int e0 = (blockIdx.x * 256 + threadIdx.x) * 4;
    if (e0 + 3 < E) {
        int4 d = *(const int4*)(dst + e0);
        int4 r;
        r.x = atomicAdd(&counts[d.x], 1);
        r.y = atomicAdd(&counts[d.y], 1);
        r.z = atomicAdd(&counts[d.z], 1);
        r.w = atomicAdd(&counts[d.w], 1);
        *(int4*)(rank + e0) = r;
    } else {
        for (int k = 0; k < 4; ++k)
            if (e0 + k < E) rank[e0 + k] = atomicAdd(&counts[dst[e0 + k]], 1);
    }
}

__global__ void k_scanA(const int* __restrict__ counts, int* __restrict__ offs,
                        int* __restrict__ bsums, int N) {
    __shared__ int buf[2][256];
    int t = threadIdx.x;
    int idx = blockIdx.x * 256 + t;
    int v = (idx < N) ? counts[idx] : 0;
    buf[0][t] = v;
    __syncthreads();
    int pi = 0;
    for (int d = 1; d < 256; d <<= 1) {
        int po = pi ^ 1;
        buf[po][t] = buf[pi][t] + (t >= d ? buf[pi][t - d] : 0);
        pi = po;
        __syncthreads();
    }
    if (idx < N) offs[idx] = buf[pi][t] - v;
    if (t == 255) bsums[blockIdx.x] = buf[pi][255];
}

__global__ void k_scanB(int* __restrict__ bsums, int nb) {
    __shared__ int buf[2][512];
    int t = threadIdx.x;
    int v = (t < nb) ? bsums[t] : 0;
    buf[0][t] = v;
    __syncthreads();
    int pi = 0;
    for (int d = 1; d < 512; d <<= 1) {
        int po = pi ^ 1;
        buf[po][t] = buf[pi][t] + (t >= d ? buf[pi][t - d] : 0);
        pi = po;
        __syncthreads();
    }
    if (t < nb) bsums[t] = buf[pi][t] - v;
}

__global__ void k_scanC(int* __restrict__ offs, const int* __restrict__ bsums, int N, int E) {
    int idx = blockIdx.x * 256 + threadIdx.x;
    if (idx < N) offs[idx] += bsums[blockIdx.x];
    if (idx == 0) offs[N] = E;
}

// ---------------- fused GEMM (+ optional CSR scatter role) ----------------
// GEMM blocks [0,nbG): 32 rows/block (N%32==0 -> no row guards).
//   LDS: X tile (32 x FIN) + W transposed so lane's 4 weights for one k4 are
//   one ds_read_b128. Inner loop: 1 lane-strided b128 + 8 uniform-broadcast
//   b128 per 32 FMAs; zero global loads (round-4 gemm was latency-bound on
//   wave-uniform global x loads).
// Scatter blocks [nbG, nbG+nbS): atomic-free CSR scatter, 4 edges/thread,
//   int4 loads; random 4B stores. Independent of the GEMM -> overlaps.

template <int FIN, bool SCATTER>
__global__ __launch_bounds__(256, 4) void k_gemm_sc(
    const float* __restrict__ x, const float* __restrict__ W,
    const float* __restrict__ al, const float* __restrict__ ar,
    __half* __restrict__ h, float* __restrict__ el, float* __restrict__ er,
    int nbG,
    const int* __restrict__ src, const int* __restrict__ dst,
    const int* __restrict__ rank, const int* __restrict__ offs,
    int* __restrict__ csr, int E) {

    if (SCATTER && (int)blockIdx.x >= nbG) {
        int e0 = ((int)blockIdx.x - nbG) * 1024 + threadIdx.x * 4;
        if (e0 + 3 < E) {
            int4 d = *(const int4*)(dst + e0);
            int4 rk = *(const int4*)(rank + e0);
            int4 s = *(const int4*)(src + e0);
            csr[offs[d.x] + rk.x] = s.x;
            csr[offs[d.y] + rk.y] = s.y;
            csr[offs[d.z] + rk.z] = s.z;
            csr[offs[d.w] + rk.w] = s.w;
        } else {
            for (int k = 0; k < 4; ++k)
                if (e0 + k < E) csr[offs[dst[e0 + k]] + rank[e0 + k]] = src[e0 + k];
        }
        return;
    }

    __shared__ float Wt[FIN * 64];   // Wt[k4*256 + c*4 + j] = W[(4k4+j)*64 + c]
    __shared__ float Xl[32 * FIN];

    // stage W transposed
    for (int idx = threadIdx.x; idx < FIN * 16; idx += 256) {
        float4 wv = ((const float4*)W)[idx];
        int k = idx >> 4;
        int c0 = (idx & 15) << 2;
        float* bp = &Wt[(k >> 2) * 256 + (k & 3)];
        bp[(c0 + 0) * 4] = wv.x;
        bp[(c0 + 1) * 4] = wv.y;
        bp[(c0 + 2) * 4] = wv.z;
        bp[(c0 + 3) * 4] = wv.w;
    }
    // stage X tile (coalesced float4)
    int row0 = blockIdx.x * 32;
    {
        const float4* xg = (const float4*)(x + (size_t)row0 * FIN);
        float4* xl4 = (float4*)Xl;
        for (int i = threadIdx.x; i < 32 * FIN / 4; i += 256) xl4[i] = xg[i];
    }
    __syncthreads();

    int wave = threadIdx.x >> 6, lane = threadIdx.x & 63;
    int rbase = wave * 8;

    float acc[8] = {0.f, 0.f, 0.f, 0.f, 0.f, 0.f, 0.f, 0.f};
    const float* xrow = &Xl[rbase * FIN];
#pragma unroll 2
    for (int k4 = 0; k4 < FIN / 4; ++k4) {
        float4 wv = *(const float4*)&Wt[k4 * 256 + lane * 4];
#pragma unroll
        for (int r = 0; r < 8; ++r) {
            float4 xv = *(const float4*)(xrow + r * FIN + k4 * 4);
            acc[r] = fmaf(xv.x, wv.x, acc[r]);
            acc[r] = fmaf(xv.y, wv.y, acc[r]);
            acc[r] = fmaf(xv.z, wv.z, acc[r]);
            acc[r] = fmaf(xv.w, wv.w, acc[r]);
        }
    }

    float all = al[lane], arl = ar[lane];
#pragma unroll
    for (int r = 0; r < 8; ++r) {
        int row = row0 + rbase + r;
        h[(size_t)row * 64 + lane] = __float2half(acc[r]);
        float e1 = acc[r] * all, e2 = acc[r] * arl;
#pragma unroll
        for (int o = 32; o; o >>= 1) {
            e1 += __shfl_xor(e1, o);
            e2 += __shfl_xor(e2, o);
        }
        if (lane == 0) { el[row] = e1; er[row] = e2; }
    }
}

// ---------------- edge softmax + aggregation (unchanged from round 4) ----------------

__device__ inline float2 h2_to_f2(float bits) {
    return __half22float2(__builtin_bit_cast(__half2, bits));
}

__global__ __launch_bounds__(256) void k_agg(const __half* __restrict__ h,
                                             const float* __restrict__ el,
                                             const float* __restrict__ er,
                                             const float* __restrict__ b,
                                             const int* __restrict__ offs,
                                             const int* __restrict__ csr_src,
                                             float* __restrict__ out, int N, int relu) {
    int wave = threadIdx.x >> 6, lane = threadIdx.x & 63;
    int n = blockIdx.x * 4 + wave;
    if (n >= N) return;

    int beg = offs[n], end = offs[n + 1];
    int deg = end - beg;
    float ern = er[n];

    int g = lane >> 4;
    int fl = lane & 15;
    float4 accv = make_float4(0.f, 0.f, 0.f, 0.f);
    const size_t foff = 4 * (size_t)fl;

    if (deg <= 64) {
        int sidx = 0;
        float e = -1e30f;
        if (lane < deg) {
            sidx = csr_src[beg + lane];
            e = el[sidx] + ern;
            e = e > 0.f ? e : NEG_SLOPE * e;
        }
        float m = e;
#pragma unroll
        for (int o = 32; o; o >>= 1) m = fmaxf(m, __shfl_xor(m, o));
        float p = (lane < deg) ? __expf(e - m) : 0.f;
        float s = p;
#pragma unroll
        for (int o = 32; o; o >>= 1) s += __shfl_xor(s, o);
        float a = p * (1.f / fmaxf(s, 1e-9f));

        int iters = (deg + 3) >> 2;   // wave-uniform trip count (shuffle safety)
        int pair = iters >> 1;
        int i = g;
        for (int t2 = 0; t2 < pair; ++t2, i += 8) {
            int s0 = __shfl(sidx, i), s1 = __shfl(sidx, i + 4);
            float w0 = __shfl(a, i), w1 = __shfl(a, i + 4);
            float2 r0 = *(const float2*)(h + (size_t)s0 * 64 + foff);
            float2 r1 = *(const float2*)(h + (size_t)s1 * 64 + foff);
            float2 f00 = h2_to_f2(r0.x), f01 = h2_to_f2(r0.y);
            float2 f10 = h2_to_f2(r1.x), f11 = h2_to_f2(r1.y);
            accv.x = fmaf(w0, f00.x, accv.x); accv.y = fmaf(w0, f00.y, accv.y);
            accv.z = fmaf(w0, f01.x, accv.z); accv.w = fmaf(w0, f01.y, accv.w);
            accv.x = fmaf(w1, f10.x, accv.x); accv.y = fmaf(w1, f10.y, accv.y);
            accv.z = fmaf(w1, f11.x, accv.z); accv.w = fmaf(w1, f11.y, accv.w);
        }
        if (iters & 1) {
            int s0 = __shfl(sidx, i);
            float w0 = __shfl(a, i);
            float2 r0 = *(const float2*)(h + (size_t)s0 * 64 + foff);
            float2 f00 = h2_to_f2(r0.x), f01 = h2_to_f2(r0.y);
            accv.x = fmaf(w0, f00.x, accv.x); accv.y = fmaf(w0, f00.y, accv.y);
            accv.z = fmaf(w0, f01.x, accv.z); accv.w = fmaf(w0, f01.y, accv.w);
        }
    } else {
        float m = -1e30f;
        for (int i = beg + lane; i < end; i += 64) {
            float e = el[csr_src[i]] + ern;
            e = e > 0.f ? e : NEG_SLOPE * e;
            m = fmaxf(m, e);
        }
#pragma unroll
        for (int o = 32; o; o >>= 1) m = fmaxf(m, __shfl_xor(m, o));
        float s = 0.f;
        for (int i = beg + lane; i < end; i += 64) {
            float e = el[csr_src[i]] + ern;
            e = e > 0.f ? e : NEG_SLOPE * e;
            s += __expf(e - m);
        }
#pragma unroll
        for (int o = 32; o; o >>= 1) s += __shfl_xor(s, o);
        float inv = 1.f / fmaxf(s, 1e-9f);

        for (int i = g; i < deg; i += 4) {
            int s0 = csr_src[beg + i];
            float e = el[s0] + ern;
            e = e > 0.f ? e : NEG_SLOPE * e;
            float w0 = __expf(e - m) * inv;
            float2 r0 = *(const float2*)(h + (size_t)s0 * 64 + foff);
            float2 f00 = h2_to_f2(r0.x), f01 = h2_to_f2(r0.y);
            accv.x = fmaf(w0, f00.x, accv.x); accv.y = fmaf(w0, f00.y, accv.y);
            accv.z = fmaf(w0, f01.x, accv.z); accv.w = fmaf(w0, f01.y, accv.w);
        }
    }

#pragma unroll
    for (int o = 16; o <= 32; o <<= 1) {
        accv.x += __shfl_xor(accv.x, o);
        accv.y += __shfl_xor(accv.y, o);
        accv.z += __shfl_xor(accv.z, o);
        accv.w += __shfl_xor(accv.w, o);
    }

    if (lane < 16) {
        float4 bv = *(const float4*)(b + foff);
        float4 o4;
        o4.x = accv.x + bv.x;
        o4.y = accv.y + bv.y;
        o4.z = accv.z + bv.z;
        o4.w = accv.w + bv.w;
        if (relu) {
            o4.x = fmaxf(o4.x, 0.f); o4.y = fmaxf(o4.y, 0.f);
            o4.z = fmaxf(o4.z, 0.f); o4.w = fmaxf(o4.w, 0.f);
        }
        *(float4*)(out + (size_t)n * 64 + foff) = o4;
    }
}

// ---------------- launch ----------------

extern "C" void kernel_launch(void* const* d_in, const int* in_sizes, int n_in,
                              void* d_out, int out_size, void* d_ws, size_t ws_size,
                              hipStream_t stream) {
    const float* x   = (const float*)d_in[0];
    const int*   src = (const int*)d_in[1];
    const int*   dst = (const int*)d_in[2];
    const float* W1  = (const float*)d_in[3];
    const float* al1 = (const float*)d_in[4];
    const float* ar1 = (const float*)d_in[5];
    const float* b1  = (const float*)d_in[6];
    const float* W2  = (const float*)d_in[7];
    const float* al2 = (const float*)d_in[8];
    const float* ar2 = (const float*)d_in[9];
    const float* b2  = (const float*)d_in[10];
    float* out = (float*)d_out;

    const int N = NNODES;
    const int E = in_sizes[1];

    // workspace (all chunks 16B-aligned: N*4 and E*4 are multiples of 16)
    __half* h   = (__half*)d_ws;                   // N*64 halfs
    float* hmid = (float*)(h + (size_t)N * 64);    // N*64 floats
    float* el   = hmid + (size_t)N * 64;           // N
    float* er   = el + N;                          // N
    int* rank   = (int*)(er + N);                  // E
    int* csr    = rank + E;                        // E
    int* counts = csr + E;                         // N
    int* offs   = counts + N;                      // N+1
    int* bsums  = offs + N + 1;                    // <=512

    int nbN = (N + 255) / 256;        // 391 (<=512 for scanB)
    int nbH = (E + 1023) / 1024;      // hist: 4 edges/thread
    int nbG = (N + 31) / 32;          // 3125 gemm blocks
    int nbS = (E + 1023) / 1024;      // 1563 scatter blocks
    int nbR = (N + 3) / 4;            // agg: wave per node

    hipMemsetAsync(counts, 0, (size_t)N * sizeof(int), stream);

    k_hist<<<nbH, 256, 0, stream>>>(dst, counts, rank, E);
    k_scanA<<<nbN, 256, 0, stream>>>(counts, offs, bsums, N);
    k_scanB<<<1, 512, 0, stream>>>(bsums, nbN);
    k_scanC<<<nbN, 256, 0, stream>>>(offs, bsums, N, E);

    // layer 1 GEMM fused with the CSR scatter (independent work, overlapped)
    k_gemm_sc<128, true><<<nbG + nbS, 256, 0, stream>>>(
        x, W1, al1, ar1, h, el, er, nbG, src, dst, rank, offs, csr, E);
    k_agg<<<nbR, 256, 0, stream>>>(h, el, er, b1, offs, csr, hmid, N, 1);
    // layer 2
    k_gemm_sc<64, false><<<nbG, 256, 0, stream>>>(
        hmid, W2, al2, ar2, h, el, er, nbG, src, dst, rank, offs, csr, E);
    k_agg<<<nbR, 256, 0, stream>>>(h, el, er, b2, offs, csr, out, N, 0);
}

// Round 6
// 256.561 us; speedup vs baseline: 4.6096x; 1.1242x over previous
//
#include <hip/hip_runtime.h>
#include <hip/hip_fp16.h>

#define NNODES 100000
#define NEG_SLOPE 0.2f
#define NBUCKET 196          // dst>>9 buckets (512 nodes each)
#define B1_EDGES 6144        // edges per bucket-pass-1 block

typedef _Float16 f16x8 __attribute__((ext_vector_type(8)));
typedef float f32x4 __attribute__((ext_vector_type(4)));

// ---------------- CSR build ----------------

__global__ void k_hist(const int* __restrict__ dst, int* __restrict__ counts, int E) {
    int e0 = (blockIdx.x * 256 + threadIdx.x) * 4;
    if (e0 + 3 < E) {
        int4 d = *(const int4*)(dst + e0);
        atomicAdd(&counts[d.x], 1);
        atomicAdd(&counts[d.y], 1);
        atomicAdd(&counts[d.z], 1);
        atomicAdd(&counts[d.w], 1);
    } else {
        for (int k = 0; k < 4; ++k)
            if (e0 + k < E) atomicAdd(&counts[dst[e0 + k]], 1);
    }
}

__global__ void k_scanA(const int* __restrict__ counts, int* __restrict__ offs,
                        int* __restrict__ bsums, int N) {
    __shared__ int buf[2][256];
    int t = threadIdx.x;
    int idx = blockIdx.x * 256 + t;
    int v = (idx < N) ? counts[idx] : 0;
    buf[0][t] = v;
    __syncthreads();
    int pi = 0;
    for (int d = 1; d < 256; d <<= 1) {
        int po = pi ^ 1;
        buf[po][t] = buf[pi][t] + (t >= d ? buf[pi][t - d] : 0);
        pi = po;
        __syncthreads();
    }
    if (idx < N) offs[idx] = buf[pi][t] - v;
    if (t == 255) bsums[blockIdx.x] = buf[pi][255];
}

__global__ void k_scanB(int* __restrict__ bsums, int nb) {
    __shared__ int buf[2][512];
    int t = threadIdx.x;
    int v = (t < nb) ? bsums[t] : 0;
    buf[0][t] = v;
    __syncthreads();
    int pi = 0;
    for (int d = 1; d < 512; d <<= 1) {
        int po = pi ^ 1;
        buf[po][t] = buf[pi][t] + (t >= d ? buf[pi][t - d] : 0);
        pi = po;
        __syncthreads();
    }
    if (t < nb) bsums[t] = buf[pi][t] - v;
}

// scanC also seeds the per-bucket cursors gcur[b] = offs[b<<9]
__global__ void k_scanC(int* __restrict__ offs, const int* __restrict__ bsums,
                        int* __restrict__ gcur, int N, int E) {
    int idx = blockIdx.x * 256 + threadIdx.x;
    if (idx < N) {
        int v = offs[idx] + bsums[blockIdx.x];
        offs[idx] = v;
        if ((idx & 511) == 0) gcur[idx >> 9] = v;
    }
    if (idx == 0) offs[N] = E;
}

// ---------------- GEMM1 (MFMA, f16) + bucket pass-1 (fused roles) ----------------
// GEMM blocks [0,nbG): 64 rows; LDS x-tile & W^T as f16, XOR-swizzled
// (byte ^= (row&7)<<4) for conflict-free ds_read_b128 fragments.
// mfma_f32_16x16x32_f16: A lane: row=l&15, k=8*(l>>4)+j; B lane: col=l&15,
// same k map (k-permutation cancels A vs B); C: col=l&15, row=4*(l>>4)+reg.
// Bucket blocks [nbG,...): bin edges by dst>>9 into be[] via LDS histogram +
// one global reservation per (block,bucket) -> coalesced-ish run writes.

__global__ __launch_bounds__(256, 4) void k_gemm1(
    const float* __restrict__ x, const float* __restrict__ W,
    const float* __restrict__ al, const float* __restrict__ ar,
    __half* __restrict__ h, float* __restrict__ el, float* __restrict__ er,
    int N, int nbG,
    const int* __restrict__ src, const int* __restrict__ dst,
    int* __restrict__ gcur, int2* __restrict__ be, int E) {

    __shared__ float4 AlR[1024];   // 16KB: 64 rows x 256B (128 f16)
    __shared__ float4 WtR[1024];   // 16KB: 64 cols x 256B (128 f16)
    __shared__ int lcnt[NBUCKET], lbase[NBUCKET], lcur[NBUCKET];

    if ((int)blockIdx.x >= nbG) {   // ---- bucket pass-1 role ----
        int base = ((int)blockIdx.x - nbG) * B1_EDGES;
        int t = threadIdx.x;
        if (t < NBUCKET) lcnt[t] = 0;
        __syncthreads();
        for (int j = 0; j < B1_EDGES / 256; ++j) {
            int e = base + j * 256 + t;
            if (e < E) atomicAdd(&lcnt[dst[e] >> 9], 1);
        }
        __syncthreads();
        if (t < NBUCKET) {
            lbase[t] = atomicAdd(&gcur[t], lcnt[t]);
            lcur[t] = 0;
        }
        __syncthreads();
        for (int j = 0; j < B1_EDGES / 256; ++j) {
            int e = base + j * 256 + t;
            if (e < E) {
                int d = dst[e];
                int p = lbase[d >> 9] + atomicAdd(&lcur[d >> 9], 1);
                be[p] = make_int2(d, src[e]);
            }
        }
        return;
    }

    // ---- GEMM role ----
    char* A = (char*)AlR;
    char* Bw = (char*)WtR;
    int tid = threadIdx.x;
    int row0 = blockIdx.x * 64;

    for (int i = tid; i < 2048; i += 256) {         // x tile: 64x128 f32 -> f16
        int r = i >> 5, c4 = i & 31;
        int rr = row0 + r; if (rr > N - 1) rr = N - 1;
        float4 v = *(const float4*)(x + (size_t)rr * 128 + c4 * 4);
        int byte = r * 256 + ((c4 * 8) ^ ((r & 7) << 4));
        *(__half2*)(A + byte)     = __floats2half2_rn(v.x, v.y);
        *(__half2*)(A + byte + 4) = __floats2half2_rn(v.z, v.w);
    }
    for (int i = tid; i < 2048; i += 256) {         // W: 128x64 -> Wt[col][k] f16
        int k = i >> 4, c4 = (i & 15) * 4;
        float4 v = *(const float4*)(W + k * 64 + c4);
        int kb = k * 2;
        *(__half*)(Bw + (c4 + 0) * 256 + (kb ^ (((c4 + 0) & 7) << 4))) = __float2half(v.x);
        *(__half*)(Bw + (c4 + 1) * 256 + (kb ^ (((c4 + 1) & 7) << 4))) = __float2half(v.y);
        *(__half*)(Bw + (c4 + 2) * 256 + (kb ^ (((c4 + 2) & 7) << 4))) = __float2half(v.z);
        *(__half*)(Bw + (c4 + 3) * 256 + (kb ^ (((c4 + 3) & 7) << 4))) = __float2half(v.w);
    }
    __syncthreads();

    int w = tid >> 6, l = tid & 63, g = l >> 4, c = l & 15;
    int swz = (c & 7) << 4;                 // (arow&7)<<4 == (col&7)<<4 == (c&7)<<4
    const char* Ar = A + (w * 16 + c) * 256;

    f32x4 acc[4];
#pragma unroll
    for (int t2 = 0; t2 < 4; ++t2) acc[t2] = (f32x4){0.f, 0.f, 0.f, 0.f};

#pragma unroll
    for (int kk = 0; kk < 4; ++kk) {
        int kb = kk * 64 + g * 16;
        f16x8 av = *(const f16x8*)(Ar + (kb ^ swz));
#pragma unroll
        for (int t2 = 0; t2 < 4; ++t2) {
            f16x8 bv = *(const f16x8*)(Bw + (t2 * 16 + c) * 256 + (kb ^ swz));
            acc[t2] = __builtin_amdgcn_mfma_f32_16x16x32_f16(av, bv, acc[t2], 0, 0, 0);
        }
    }

    float alv[4], arv[4];
#pragma unroll
    for (int t2 = 0; t2 < 4; ++t2) { alv[t2] = al[t2 * 16 + c]; arv[t2] = ar[t2 * 16 + c]; }
#pragma unroll
    for (int r = 0; r < 4; ++r) {
        float e1 = 0.f, e2 = 0.f;
#pragma unroll
        for (int t2 = 0; t2 < 4; ++t2) {
            e1 = fmaf(acc[t2][r], alv[t2], e1);
            e2 = fmaf(acc[t2][r], arv[t2], e2);
        }
#pragma unroll
        for (int o = 1; o < 16; o <<= 1) { e1 += __shfl_xor(e1, o); e2 += __shfl_xor(e2, o); }
        int row = row0 + w * 16 + 4 * g + r;
        if (row < N) {
            if (c == 0) { el[row] = e1; er[row] = e2; }
#pragma unroll
            for (int t2 = 0; t2 < 4; ++t2)
                h[(size_t)row * 64 + t2 * 16 + c] = __float2half(acc[t2][r]);
        }
    }
}

// ---------------- GEMM2 (MFMA, f16 in/out) ----------------

__global__ __launch_bounds__(256, 4) void k_gemm2(
    const __half* __restrict__ xin, const float* __restrict__ W,
    const float* __restrict__ al, const float* __restrict__ ar,
    __half* __restrict__ h, float* __restrict__ el, float* __restrict__ er, int N) {

    __shared__ float4 AlR[512];    // 8KB: 64 rows x 128B (64 f16)
    __shared__ float4 WtR[512];    // 8KB: 64 cols x 128B

    char* A = (char*)AlR;
    char* Bw = (char*)WtR;
    int tid = threadIdx.x;
    int row0 = blockIdx.x * 64;

    for (int i = tid; i < 512; i += 256) {          // x tile: direct f16 copy
        int r = i >> 3, o = i & 7;
        int rr = row0 + r; if (rr > N - 1) rr = N - 1;
        float4 v = *(const float4*)(xin + (size_t)rr * 64 + o * 8);
        *(float4*)(A + r * 128 + ((o * 16) ^ ((r & 7) << 4))) = v;
    }
    for (int i = tid; i < 1024; i += 256) {         // W2: 64x64 f32 -> Wt f16
        int k = i >> 4, c4 = (i & 15) * 4;
        float4 v = *(const float4*)(W + k * 64 + c4);
        int kb = k * 2;
        *(__half*)(Bw + (c4 + 0) * 128 + (kb ^ (((c4 + 0) & 7) << 4))) = __float2half(v.x);
        *(__half*)(Bw + (c4 + 1) * 128 + (kb ^ (((c4 + 1) & 7) << 4))) = __float2half(v.y);
        *(__half*)(Bw + (c4 + 2) * 128 + (kb ^ (((c4 + 2) & 7) << 4))) = __float2half(v.z);
        *(__half*)(Bw + (c4 + 3) * 128 + (kb ^ (((c4 + 3) & 7) << 4))) = __float2half(v.w);
    }
    __syncthreads();

    int w = tid >> 6, l = tid & 63, g = l >> 4, c = l & 15;
    int swz = (c & 7) << 4;
    const char* Ar = A + (w * 16 + c) * 128;

    f32x4 acc[4];
#pragma unroll
    for (int t2 = 0; t2 < 4; ++t2) acc[t2] = (f32x4){0.f, 0.f, 0.f, 0.f};

#pragma unroll
    for (int kk = 0; kk < 2; ++kk) {
        int kb = kk * 64 + g * 16;
        f16x8 av = *(const f16x8*)(Ar + (kb ^ swz));
#pragma unroll
        for (int t2 = 0; t2 < 4; ++t2) {
            f16x8 bv = *(const f16x8*)(Bw + (t2 * 16 + c) * 128 + (kb ^ swz));
            acc[t2] = __builtin_amdgcn_mfma_f32_16x16x32_f16(av, bv, acc[t2], 0, 0, 0);
        }
    }

    float alv[4], arv[4];
#pragma unroll
    for (int t2 = 0; t2 < 4; ++t2) { alv[t2] = al[t2 * 16 + c]; arv[t2] = ar[t2 * 16 + c]; }
#pragma unroll
    for (int r = 0; r < 4; ++r) {
        float e1 = 0.f, e2 = 0.f;
#pragma unroll
        for (int t2 = 0; t2 < 4; ++t2) {
            e1 = fmaf(acc[t2][r], alv[t2], e1);
            e2 = fmaf(acc[t2][r], arv[t2], e2);
        }
#pragma unroll
        for (int o = 1; o < 16; o <<= 1) { e1 += __shfl_xor(e1, o); e2 += __shfl_xor(e2, o); }
        int row = row0 + w * 16 + 4 * g + r;
        if (row < N) {
            if (c == 0) { el[row] = e1; er[row] = e2; }
#pragma unroll
            for (int t2 = 0; t2 < 4; ++t2)
                h[(size_t)row * 64 + t2 * 16 + c] = __float2half(acc[t2][r]);
        }
    }
}

// ---------------- bucket pass-2: per-bucket fine scatter ----------------
// One block per 512-node bucket: csr writes land in a ~32KB window -> stay in
// one XCD's L2, no cross-XCD line bounce (round-4/5 scatter wrote 107MB for a
// 6.4MB array).

__global__ __launch_bounds__(256) void k_scatter2(const int2* __restrict__ be,
                                                  const int* __restrict__ offs,
                                                  int* __restrict__ csr, int N, int E) {
    __shared__ int cur[512];
    int b = blockIdx.x;
    int t = threadIdx.x;
    cur[t] = 0; cur[t + 256] = 0;
    __syncthreads();
    int rbeg = offs[b << 9];
    int nend = (b + 1) << 9; if (nend > N) nend = N;
    int rend = offs[nend];
    for (int i = rbeg + t; i < rend; i += 256) {
        int2 e = be[i];
        int r = atomicAdd(&cur[e.x & 511], 1);
        csr[offs[e.x] + r] = e.y;
    }
}

// ---------------- edge softmax + aggregation ----------------
// One wave per dst node; single-pass softmax (deg<=64); gather split into
// 4 groups x 16 lanes; wave-uniform trip count (shuffle-safety, round-3 bug).

__device__ inline float2 h2_to_f2(float bits) {
    return __half22float2(__builtin_bit_cast(__half2, bits));
}

template <bool OUT_HALF>
__global__ __launch_bounds__(256) void k_agg(const __half* __restrict__ h,
                                             const float* __restrict__ el,
                                             const float* __restrict__ er,
                                             const float* __restrict__ b,
                                             const int* __restrict__ offs,
                                             const int* __restrict__ csr_src,
                                             void* __restrict__ outp, int N, int relu) {
    int wave = threadIdx.x >> 6, lane = threadIdx.x & 63;
    int n = blockIdx.x * 4 + wave;
    if (n >= N) return;

    int beg = offs[n], end = offs[n + 1];
    int deg = end - beg;
    float ern = er[n];

    int g = lane >> 4;
    int fl = lane & 15;
    float4 accv = make_float4(0.f, 0.f, 0.f, 0.f);
    const size_t foff = 4 * (size_t)fl;

    if (deg <= 64) {
        int sidx = 0;
        float e = -1e30f;
        if (lane < deg) {
            sidx = csr_src[beg + lane];
            e = el[sidx] + ern;
            e = e > 0.f ? e : NEG_SLOPE * e;
        }
        float m = e;
#pragma unroll
        for (int o = 32; o; o >>= 1) m = fmaxf(m, __shfl_xor(m, o));
        float p = (lane < deg) ? __expf(e - m) : 0.f;
        float s = p;
#pragma unroll
        for (int o = 32; o; o >>= 1) s += __shfl_xor(s, o);
        float a = p * (1.f / fmaxf(s, 1e-9f));

        int iters = (deg + 3) >> 2;   // wave-uniform
        int pair = iters >> 1;
        int i = g;
        for (int t2 = 0; t2 < pair; ++t2, i += 8) {
            int s0 = __shfl(sidx, i), s1 = __shfl(sidx, i + 4);
            float w0 = __shfl(a, i), w1 = __shfl(a, i + 4);
            float2 r0 = *(const float2*)(h + (size_t)s0 * 64 + foff);
            float2 r1 = *(const float2*)(h + (size_t)s1 * 64 + foff);
            float2 f00 = h2_to_f2(r0.x), f01 = h2_to_f2(r0.y);
            float2 f10 = h2_to_f2(r1.x), f11 = h2_to_f2(r1.y);
            accv.x = fmaf(w0, f00.x, accv.x); accv.y = fmaf(w0, f00.y, accv.y);
            accv.z = fmaf(w0, f01.x, accv.z); accv.w = fmaf(w0, f01.y, accv.w);
            accv.x = fmaf(w1, f10.x, accv.x); accv.y = fmaf(w1, f10.y, accv.y);
            accv.z = fmaf(w1, f11.x, accv.z); accv.w = fmaf(w1, f11.y, accv.w);
        }
        if (iters & 1) {
            int s0 = __shfl(sidx, i);
            float w0 = __shfl(a, i);
            float2 r0 = *(const float2*)(h + (size_t)s0 * 64 + foff);
            float2 f00 = h2_to_f2(r0.x), f01 = h2_to_f2(r0.y);
            accv.x = fmaf(w0, f00.x, accv.x); accv.y = fmaf(w0, f00.y, accv.y);
            accv.z = fmaf(w0, f01.x, accv.z); accv.w = fmaf(w0, f01.y, accv.w);
        }
    } else {
        float m = -1e30f;
        for (int i = beg + lane; i < end; i += 64) {
            float e = el[csr_src[i]] + ern;
            e = e > 0.f ? e : NEG_SLOPE * e;
            m = fmaxf(m, e);
        }
#pragma unroll
        for (int o = 32; o; o >>= 1) m = fmaxf(m, __shfl_xor(m, o));
        float s = 0.f;
        for (int i = beg + lane; i < end; i += 64) {
            float e = el[csr_src[i]] + ern;
            e = e > 0.f ? e : NEG_SLOPE * e;
            s += __expf(e - m);
        }
#pragma unroll
        for (int o = 32; o; o >>= 1) s += __shfl_xor(s, o);
        float inv = 1.f / fmaxf(s, 1e-9f);

        for (int i = g; i < deg; i += 4) {
            int s0 = csr_src[beg + i];
            float e = el[s0] + ern;
            e = e > 0.f ? e : NEG_SLOPE * e;
            float w0 = __expf(e - m) * inv;
            float2 r0 = *(const float2*)(h + (size_t)s0 * 64 + foff);
            float2 f00 = h2_to_f2(r0.x), f01 = h2_to_f2(r0.y);
            accv.x = fmaf(w0, f00.x, accv.x); accv.y = fmaf(w0, f00.y, accv.y);
            accv.z = fmaf(w0, f01.x, accv.z); accv.w = fmaf(w0, f01.y, accv.w);
        }
    }

#pragma unroll
    for (int o = 16; o <= 32; o <<= 1) {
        accv.x += __shfl_xor(accv.x, o);
        accv.y += __shfl_xor(accv.y, o);
        accv.z += __shfl_xor(accv.z, o);
        accv.w += __shfl_xor(accv.w, o);
    }

    if (lane < 16) {
        float4 bv = *(const float4*)(b + foff);
        float ox = accv.x + bv.x, oy = accv.y + bv.y;
        float oz = accv.z + bv.z, ow = accv.w + bv.w;
        if (relu) {
            ox = fmaxf(ox, 0.f); oy = fmaxf(oy, 0.f);
            oz = fmaxf(oz, 0.f); ow = fmaxf(ow, 0.f);
        }
        if (OUT_HALF) {
            __half* oh = (__half*)outp + (size_t)n * 64 + foff;
            *(__half2*)(oh)     = __floats2half2_rn(ox, oy);
            *(__half2*)(oh + 2) = __floats2half2_rn(oz, ow);
        } else {
            *(float4*)((float*)outp + (size_t)n * 64 + foff) = make_float4(ox, oy, oz, ow);
        }
    }
}

// ---------------- launch ----------------

extern "C" void kernel_launch(void* const* d_in, const int* in_sizes, int n_in,
                              void* d_out, int out_size, void* d_ws, size_t ws_size,
                              hipStream_t stream) {
    const float* x   = (const float*)d_in[0];
    const int*   src = (const int*)d_in[1];
    const int*   dst = (const int*)d_in[2];
    const float* W1  = (const float*)d_in[3];
    const float* al1 = (const float*)d_in[4];
    const float* ar1 = (const float*)d_in[5];
    const float* b1  = (const float*)d_in[6];
    const float* W2  = (const float*)d_in[7];
    const float* al2 = (const float*)d_in[8];
    const float* ar2 = (const float*)d_in[9];
    const float* b2  = (const float*)d_in[10];
    float* out = (float*)d_out;

    const int N = NNODES;
    const int E = in_sizes[1];

    // workspace (16B-aligned chunks)
    __half* h    = (__half*)d_ws;                    // N*64 f16 (12.8MB)
    __half* hmid = h + (size_t)N * 64;               // N*64 f16 (12.8MB)
    int2*   be   = (int2*)(hmid + (size_t)N * 64);   // E int2 (12.8MB)
    int*    csr  = (int*)(be + E);                   // E (6.4MB)
    float*  el   = (float*)(csr + E);                // N
    float*  er   = el + N;                           // N
    int* counts  = (int*)(er + N);                   // N
    int* offs    = counts + N;                       // N+1
    int* bsums   = offs + N + 1;                     // <=512
    int* gcur    = bsums + 512;                      // NBUCKET

    int nbN = (N + 255) / 256;          // 391
    int nbH = (E + 1023) / 1024;
    int nbG = (N + 63) / 64;            // 1563
    int nbB = (E + B1_EDGES - 1) / B1_EDGES;  // 261
    int nbR = (N + 3) / 4;              // 25000

    hipMemsetAsync(counts, 0, (size_t)N * sizeof(int), stream);

    k_hist<<<nbH, 256, 0, stream>>>(dst, counts, E);
    k_scanA<<<nbN, 256, 0, stream>>>(counts, offs, bsums, N);
    k_scanB<<<1, 512, 0, stream>>>(bsums, nbN);
    k_scanC<<<nbN, 256, 0, stream>>>(offs, bsums, gcur, N, E);

    // layer-1 GEMM (MFMA) fused with bucket pass-1 (independent work)
    k_gemm1<<<nbG + nbB, 256, 0, stream>>>(x, W1, al1, ar1, h, el, er, N, nbG,
                                           src, dst, gcur, be, E);
    k_scatter2<<<NBUCKET, 256, 0, stream>>>(be, offs, csr, N, E);

    k_agg<true><<<nbR, 256, 0, stream>>>(h, el, er, b1, offs, csr, hmid, N, 1);
    k_gemm2<<<nbG, 256, 0, stream>>>(hmid, W2, al2, ar2, h, el, er, N);
    k_agg<false><<<nbR, 256, 0, stream>>>(h, el, er, b2, offs, csr, out, N, 0);
}

// Round 7
// 200.819 us; speedup vs baseline: 5.8892x; 1.2776x over previous
//
#include <hip/hip_runtime.h>
#include <hip/hip_fp16.h>

#define NNODES 100000
#define NEG_SLOPE 0.2f
#define NB2 391          // buckets of 256 nodes (dst>>8), covers N=100000
#define BCAP 4864        // be[] slots per bucket; mean 4092, ~12 sigma slack
#define B1_EDGES 2048    // edges per bucket-pass-1 block

typedef _Float16 f16x8 __attribute__((ext_vector_type(8)));
typedef float f32x4 __attribute__((ext_vector_type(4)));

// ---------------- init: bucket cursors + offs[N] ----------------
// Replaces k_hist + 3 scan kernels (round 6: hist alone was 68us with 50MB of
// device-scope atomic write traffic). Buckets get fixed-capacity regions.

__global__ void k_init(int* __restrict__ gcur, int* __restrict__ offs, int N, int E) {
    int t = blockIdx.x * 256 + threadIdx.x;
    if (t < NB2) gcur[t] = t * BCAP;
    if (t == NB2) offs[N] = E;
}

// ---------------- GEMM1 (MFMA, f16) + bucket pass-1 (fused roles) ----------------
// Bucket blocks are FIRST (blockIdx < nbB) so they dispatch early and overlap
// under the gemm blocks (round 6: as a tail they serialized 68us).
// Pass-1: LDS histogram by dst>>8, one global reservation per (block,bucket),
// then bin edges into be[]. GEMM role: 64 rows/block, x & W^T staged as f16
// with XOR swizzle (byte ^= (row&7)<<4), mfma_f32_16x16x32_f16.

__global__ __launch_bounds__(256, 4) void k_gemm1(
    const float* __restrict__ x, const float* __restrict__ W,
    const float* __restrict__ al, const float* __restrict__ ar,
    __half* __restrict__ h, float* __restrict__ el, float* __restrict__ er,
    int N, int nbB,
    const int* __restrict__ src, const int* __restrict__ dst,
    int* __restrict__ gcur, int2* __restrict__ be, int E) {

    __shared__ float4 AlR[1024];   // 16KB
    __shared__ float4 WtR[1024];   // 16KB
    __shared__ int lcnt[NB2], lbase[NB2], lcur[NB2];

    int t = threadIdx.x;

    if ((int)blockIdx.x < nbB) {   // ---- bucket pass-1 role ----
        int base = (int)blockIdx.x * B1_EDGES;
        for (int j = t; j < NB2; j += 256) lcnt[j] = 0;
        __syncthreads();
#pragma unroll
        for (int j = 0; j < B1_EDGES / 256; ++j) {
            int e = base + j * 256 + t;
            if (e < E) atomicAdd(&lcnt[dst[e] >> 8], 1);
        }
        __syncthreads();
        for (int j = t; j < NB2; j += 256) {
            lbase[j] = atomicAdd(&gcur[j], lcnt[j]);
            lcur[j] = 0;
        }
        __syncthreads();
#pragma unroll
        for (int j = 0; j < B1_EDGES / 256; ++j) {
            int e = base + j * 256 + t;
            if (e < E) {
                int d = dst[e];
                int bk = d >> 8;
                int p = lbase[bk] + atomicAdd(&lcur[bk], 1);
                be[p] = make_int2(d, src[e]);
            }
        }
        return;
    }

    // ---- GEMM role ----
    char* A = (char*)AlR;
    char* Bw = (char*)WtR;
    int row0 = ((int)blockIdx.x - nbB) * 64;

    for (int i = t; i < 2048; i += 256) {           // x: 64x128 f32 -> f16 swz
        int r = i >> 5, c4 = i & 31;
        int rr = row0 + r; if (rr > N - 1) rr = N - 1;
        float4 v = *(const float4*)(x + (size_t)rr * 128 + c4 * 4);
        int byte = r * 256 + ((c4 * 8) ^ ((r & 7) << 4));
        *(__half2*)(A + byte)     = __floats2half2_rn(v.x, v.y);
        *(__half2*)(A + byte + 4) = __floats2half2_rn(v.z, v.w);
    }
    for (int i = t; i < 2048; i += 256) {           // W: 128x64 -> Wt[col][k]
        int k = i >> 4, c4 = (i & 15) * 4;
        float4 v = *(const float4*)(W + k * 64 + c4);
        int kb = k * 2;
        *(__half*)(Bw + (c4 + 0) * 256 + (kb ^ (((c4 + 0) & 7) << 4))) = __float2half(v.x);
        *(__half*)(Bw + (c4 + 1) * 256 + (kb ^ (((c4 + 1) & 7) << 4))) = __float2half(v.y);
        *(__half*)(Bw + (c4 + 2) * 256 + (kb ^ (((c4 + 2) & 7) << 4))) = __float2half(v.z);
        *(__half*)(Bw + (c4 + 3) * 256 + (kb ^ (((c4 + 3) & 7) << 4))) = __float2half(v.w);
    }
    __syncthreads();

    int w = t >> 6, l = t & 63, g = l >> 4, c = l & 15;
    int swz = (c & 7) << 4;
    const char* Ar = A + (w * 16 + c) * 256;

    f32x4 acc[4];
#pragma unroll
    for (int t2 = 0; t2 < 4; ++t2) acc[t2] = (f32x4){0.f, 0.f, 0.f, 0.f};

#pragma unroll
    for (int kk = 0; kk < 4; ++kk) {
        int kb = kk * 64 + g * 16;
        f16x8 av = *(const f16x8*)(Ar + (kb ^ swz));
#pragma unroll
        for (int t2 = 0; t2 < 4; ++t2) {
            f16x8 bv = *(const f16x8*)(Bw + (t2 * 16 + c) * 256 + (kb ^ swz));
            acc[t2] = __builtin_amdgcn_mfma_f32_16x16x32_f16(av, bv, acc[t2], 0, 0, 0);
        }
    }

    float alv[4], arv[4];
#pragma unroll
    for (int t2 = 0; t2 < 4; ++t2) { alv[t2] = al[t2 * 16 + c]; arv[t2] = ar[t2 * 16 + c]; }
#pragma unroll
    for (int r = 0; r < 4; ++r) {
        float e1 = 0.f, e2 = 0.f;
#pragma unroll
        for (int t2 = 0; t2 < 4; ++t2) {
            e1 = fmaf(acc[t2][r], alv[t2], e1);
            e2 = fmaf(acc[t2][r], arv[t2], e2);
        }
#pragma unroll
        for (int o = 1; o < 16; o <<= 1) { e1 += __shfl_xor(e1, o); e2 += __shfl_xor(e2, o); }
        int row = row0 + w * 16 + 4 * g + r;
        if (row < N) {
            if (c == 0) { el[row] = e1; er[row] = e2; }
#pragma unroll
            for (int t2 = 0; t2 < 4; ++t2)
                h[(size_t)row * 64 + t2 * 16 + c] = __float2half(acc[t2][r]);
        }
    }
}

// ---------------- GEMM2 (MFMA, f16 in/out) ----------------

__global__ __launch_bounds__(256, 4) void k_gemm2(
    const __half* __restrict__ xin, const float* __restrict__ W,
    const float* __restrict__ al, const float* __restrict__ ar,
    __half* __restrict__ h, float* __restrict__ el, float* __restrict__ er, int N) {

    __shared__ float4 AlR[512];
    __shared__ float4 WtR[512];

    char* A = (char*)AlR;
    char* Bw = (char*)WtR;
    int tid = threadIdx.x;
    int row0 = blockIdx.x * 64;

    for (int i = tid; i < 512; i += 256) {
        int r = i >> 3, o = i & 7;
        int rr = row0 + r; if (rr > N - 1) rr = N - 1;
        float4 v = *(const float4*)(xin + (size_t)rr * 64 + o * 8);
        *(float4*)(A + r * 128 + ((o * 16) ^ ((r & 7) << 4))) = v;
    }
    for (int i = tid; i < 1024; i += 256) {
        int k = i >> 4, c4 = (i & 15) * 4;
        float4 v = *(const float4*)(W + k * 64 + c4);
        int kb = k * 2;
        *(__half*)(Bw + (c4 + 0) * 128 + (kb ^ (((c4 + 0) & 7) << 4))) = __float2half(v.x);
        *(__half*)(Bw + (c4 + 1) * 128 + (kb ^ (((c4 + 1) & 7) << 4))) = __float2half(v.y);
        *(__half*)(Bw + (c4 + 2) * 128 + (kb ^ (((c4 + 2) & 7) << 4))) = __float2half(v.z);
        *(__half*)(Bw + (c4 + 3) * 128 + (kb ^ (((c4 + 3) & 7) << 4))) = __float2half(v.w);
    }
    __syncthreads();

    int w = tid >> 6, l = tid & 63, g = l >> 4, c = l & 15;
    int swz = (c & 7) << 4;
    const char* Ar = A + (w * 16 + c) * 128;

    f32x4 acc[4];
#pragma unroll
    for (int t2 = 0; t2 < 4; ++t2) acc[t2] = (f32x4){0.f, 0.f, 0.f, 0.f};

#pragma unroll
    for (int kk = 0; kk < 2; ++kk) {
        int kb = kk * 64 + g * 16;
        f16x8 av = *(const f16x8*)(Ar + (kb ^ swz));
#pragma unroll
        for (int t2 = 0; t2 < 4; ++t2) {
            f16x8 bv = *(const f16x8*)(Bw + (t2 * 16 + c) * 128 + (kb ^ swz));
            acc[t2] = __builtin_amdgcn_mfma_f32_16x16x32_f16(av, bv, acc[t2], 0, 0, 0);
        }
    }

    float alv[4], arv[4];
#pragma unroll
    for (int t2 = 0; t2 < 4; ++t2) { alv[t2] = al[t2 * 16 + c]; arv[t2] = ar[t2 * 16 + c]; }
#pragma unroll
    for (int r = 0; r < 4; ++r) {
        float e1 = 0.f, e2 = 0.f;
#pragma unroll
        for (int t2 = 0; t2 < 4; ++t2) {
            e1 = fmaf(acc[t2][r], alv[t2], e1);
            e2 = fmaf(acc[t2][r], arv[t2], e2);
        }
#pragma unroll
        for (int o = 1; o < 16; o <<= 1) { e1 += __shfl_xor(e1, o); e2 += __shfl_xor(e2, o); }
        int row = row0 + w * 16 + 4 * g + r;
        if (row < N) {
            if (c == 0) { el[row] = e1; er[row] = e2; }
#pragma unroll
            for (int t2 = 0; t2 < 4; ++t2)
                h[(size_t)row * 64 + t2 * 16 + c] = __float2half(acc[t2][r]);
        }
    }
}

// ---------------- bucket pass-2: per-bucket scatter + offs production ----------------
// One block per 256-node bucket. Computes its global base by summing bucket
// counts (gcur[b]-b*BCAP), LDS-histograms its edges per node, scans, WRITES
// offs[] (replacing the old global scan pipeline), then scatters csr within a
// 16KB window (single-L2 locality).

__global__ __launch_bounds__(256) void k_scatter2(const int2* __restrict__ be,
                                                  const int* __restrict__ gcur,
                                                  int* __restrict__ offs,
                                                  int* __restrict__ csr, int N, int E) {
    __shared__ int cur[256];
    __shared__ int sbuf[2][256];
    __shared__ int rbeg_s;

    int b = blockIdx.x;
    int t = threadIdx.x;
    int mycnt = gcur[b] - b * BCAP;
    int ebase = b * BCAP;

    if (t == 0) rbeg_s = 0;
    cur[t] = 0;
    __syncthreads();

    int part = 0;
    for (int j = t; j < b; j += 256) part += gcur[j] - j * BCAP;
    if (part) atomicAdd(&rbeg_s, part);

    for (int i = t; i < mycnt; i += 256) atomicAdd(&cur[be[ebase + i].x & 255], 1);
    __syncthreads();

    // exclusive scan of cur[256]
    int v = cur[t];
    sbuf[0][t] = v;
    __syncthreads();
    int pi = 0;
    for (int d = 1; d < 256; d <<= 1) {
        int po = pi ^ 1;
        sbuf[po][t] = sbuf[pi][t] + (t >= d ? sbuf[pi][t - d] : 0);
        pi = po;
        __syncthreads();
    }
    int abs0 = rbeg_s + sbuf[pi][t] - v;

    int node = (b << 8) + t;
    if (node < N) offs[node] = abs0;
    __syncthreads();
    cur[t] = abs0;           // absolute cursor
    __syncthreads();

    for (int i = t; i < mycnt; i += 256) {
        int2 e = be[ebase + i];
        int p = atomicAdd(&cur[e.x & 255], 1);
        csr[p] = e.y;
    }
}

// ---------------- edge softmax + aggregation ----------------

__device__ inline float2 h2_to_f2(float bits) {
    return __half22float2(__builtin_bit_cast(__half2, bits));
}

template <bool OUT_HALF>
__global__ __launch_bounds__(256) void k_agg(const __half* __restrict__ h,
                                             const float* __restrict__ el,
                                             const float* __restrict__ er,
                                             const float* __restrict__ b,
                                             const int* __restrict__ offs,
                                             const int* __restrict__ csr_src,
                                             void* __restrict__ outp, int N, int relu) {
    int wave = threadIdx.x >> 6, lane = threadIdx.x & 63;
    int n = blockIdx.x * 4 + wave;
    if (n >= N) return;

    int beg = offs[n], end = offs[n + 1];
    int deg = end - beg;
    float ern = er[n];

    int g = lane >> 4;
    int fl = lane & 15;
    float4 accv = make_float4(0.f, 0.f, 0.f, 0.f);
    const size_t foff = 4 * (size_t)fl;

    if (deg <= 64) {
        int sidx = 0;
        float e = -1e30f;
        if (lane < deg) {
            sidx = csr_src[beg + lane];
            e = el[sidx] + ern;
            e = e > 0.f ? e : NEG_SLOPE * e;
        }
        float m = e;
#pragma unroll
        for (int o = 32; o; o >>= 1) m = fmaxf(m, __shfl_xor(m, o));
        float p = (lane < deg) ? __expf(e - m) : 0.f;
        float s = p;
#pragma unroll
        for (int o = 32; o; o >>= 1) s += __shfl_xor(s, o);
        float a = p * (1.f / fmaxf(s, 1e-9f));

        int iters = (deg + 3) >> 2;   // wave-uniform (shuffle safety, round-3 bug)
        int pair = iters >> 1;
        int i = g;
        for (int t2 = 0; t2 < pair; ++t2, i += 8) {
            int s0 = __shfl(sidx, i), s1 = __shfl(sidx, i + 4);
            float w0 = __shfl(a, i), w1 = __shfl(a, i + 4);
            float2 r0 = *(const float2*)(h + (size_t)s0 * 64 + foff);
            float2 r1 = *(const float2*)(h + (size_t)s1 * 64 + foff);
            float2 f00 = h2_to_f2(r0.x), f01 = h2_to_f2(r0.y);
            float2 f10 = h2_to_f2(r1.x), f11 = h2_to_f2(r1.y);
            accv.x = fmaf(w0, f00.x, accv.x); accv.y = fmaf(w0, f00.y, accv.y);
            accv.z = fmaf(w0, f01.x, accv.z); accv.w = fmaf(w0, f01.y, accv.w);
            accv.x = fmaf(w1, f10.x, accv.x); accv.y = fmaf(w1, f10.y, accv.y);
            accv.z = fmaf(w1, f11.x, accv.z); accv.w = fmaf(w1, f11.y, accv.w);
        }
        if (iters & 1) {
            int s0 = __shfl(sidx, i);
            float w0 = __shfl(a, i);
            float2 r0 = *(const float2*)(h + (size_t)s0 * 64 + foff);
            float2 f00 = h2_to_f2(r0.x), f01 = h2_to_f2(r0.y);
            accv.x = fmaf(w0, f00.x, accv.x); accv.y = fmaf(w0, f00.y, accv.y);
            accv.z = fmaf(w0, f01.x, accv.z); accv.w = fmaf(w0, f01.y, accv.w);
        }
    } else {
        float m = -1e30f;
        for (int i = beg + lane; i < end; i += 64) {
            float e = el[csr_src[i]] + ern;
            e = e > 0.f ? e : NEG_SLOPE * e;
            m = fmaxf(m, e);
        }
#pragma unroll
        for (int o = 32; o; o >>= 1) m = fmaxf(m, __shfl_xor(m, o));
        float s = 0.f;
        for (int i = beg + lane; i < end; i += 64) {
            float e = el[csr_src[i]] + ern;
            e = e > 0.f ? e : NEG_SLOPE * e;
            s += __expf(e - m);
        }
#pragma unroll
        for (int o = 32; o; o >>= 1) s += __shfl_xor(s, o);
        float inv = 1.f / fmaxf(s, 1e-9f);

        for (int i = g; i < deg; i += 4) {
            int s0 = csr_src[beg + i];
            float e = el[s0] + ern;
            e = e > 0.f ? e : NEG_SLOPE * e;
            float w0 = __expf(e - m) * inv;
            float2 r0 = *(const float2*)(h + (size_t)s0 * 64 + foff);
            float2 f00 = h2_to_f2(r0.x), f01 = h2_to_f2(r0.y);
            accv.x = fmaf(w0, f00.x, accv.x); accv.y = fmaf(w0, f00.y, accv.y);
            accv.z = fmaf(w0, f01.x, accv.z); accv.w = fmaf(w0, f01.y, accv.w);
        }
    }

#pragma unroll
    for (int o = 16; o <= 32; o <<= 1) {
        accv.x += __shfl_xor(accv.x, o);
        accv.y += __shfl_xor(accv.y, o);
        accv.z += __shfl_xor(accv.z, o);
        accv.w += __shfl_xor(accv.w, o);
    }

    if (lane < 16) {
        float4 bv = *(const float4*)(b + foff);
        float ox = accv.x + bv.x, oy = accv.y + bv.y;
        float oz = accv.z + bv.z, ow = accv.w + bv.w;
        if (relu) {
            ox = fmaxf(ox, 0.f); oy = fmaxf(oy, 0.f);
            oz = fmaxf(oz, 0.f); ow = fmaxf(ow, 0.f);
        }
        if (OUT_HALF) {
            __half* oh = (__half*)outp + (size_t)n * 64 + foff;
            *(__half2*)(oh)     = __floats2half2_rn(ox, oy);
            *(__half2*)(oh + 2) = __floats2half2_rn(oz, ow);
        } else {
            *(float4*)((float*)outp + (size_t)n * 64 + foff) = make_float4(ox, oy, oz, ow);
        }
    }
}

// ---------------- launch ----------------

extern "C" void kernel_launch(void* const* d_in, const int* in_sizes, int n_in,
                              void* d_out, int out_size, void* d_ws, size_t ws_size,
                              hipStream_t stream) {
    const float* x   = (const float*)d_in[0];
    const int*   src = (const int*)d_in[1];
    const int*   dst = (const int*)d_in[2];
    const float* W1  = (const float*)d_in[3];
    const float* al1 = (const float*)d_in[4];
    const float* ar1 = (const float*)d_in[5];
    const float* b1  = (const float*)d_in[6];
    const float* W2  = (const float*)d_in[7];
    const float* al2 = (const float*)d_in[8];
    const float* ar2 = (const float*)d_in[9];
    const float* b2  = (const float*)d_in[10];
    float* out = (float*)d_out;

    const int N = NNODES;
    const int E = in_sizes[1];

    // workspace; hmid ALIASES be (be is dead once k_scatter2 completes,
    // hmid is first written by the subsequent k_agg<true>)
    __half* h    = (__half*)d_ws;                        // N*64 f16 (12.8MB)
    int2*   be   = (int2*)(h + (size_t)N * 64);          // NB2*BCAP int2 (15.2MB)
    __half* hmid = (__half*)be;                          // N*64 f16 (aliases be)
    int*    csr  = (int*)(be + (size_t)NB2 * BCAP);      // E (6.4MB)
    float*  el   = (float*)(csr + E);                    // N
    float*  er   = el + N;                               // N
    int*    offs = (int*)(er + N);                       // N+1
    int*    gcur = offs + N + 1;                         // NB2

    int nbB = (E + B1_EDGES - 1) / B1_EDGES;   // 782
    int nbG = (N + 63) / 64;                   // 1563
    int nbR = (N + 3) / 4;                     // 25000

    k_init<<<2, 256, 0, stream>>>(gcur, offs, N, E);

    // layer-1 GEMM (MFMA) fused with bucket pass-1 (bucket blocks first)
    k_gemm1<<<nbB + nbG, 256, 0, stream>>>(x, W1, al1, ar1, h, el, er, N, nbB,
                                           src, dst, gcur, be, E);
    k_scatter2<<<NB2, 256, 0, stream>>>(be, gcur, offs, csr, N, E);

    k_agg<true><<<nbR, 256, 0, stream>>>(h, el, er, b1, offs, csr, hmid, N, 1);
    k_gemm2<<<nbG, 256, 0, stream>>>(hmid, W2, al2, ar2, h, el, er, N);
    k_agg<false><<<nbR, 256, 0, stream>>>(h, el, er, b2, offs, csr, out, N, 0);
}